// Round 1
// baseline (255.092 us; speedup 1.0000x reference)
//
#include <hip/hip_runtime.h>
#include <hip/hip_bf16.h>
#include <math.h>

typedef __bf16 bf16x8 __attribute__((ext_vector_type(8)));
typedef float f32x4 __attribute__((ext_vector_type(4)));

#define GAS __attribute__((address_space(1)))
#define LAS __attribute__((address_space(3)))

static __device__ __forceinline__ void load16(const void* g, void* l) {
    __builtin_amdgcn_global_load_lds((const GAS void*)g, (LAS void*)l, 16, 0, 0);
}

struct __align__(8) bh4 { __hip_bfloat16 x, y, z, w; };

// ---------------- LayerNorm: one wave per row of 1024 fp32 -> bf16 ----------------
__global__ __launch_bounds__(256) void ln_kernel(
        const float* __restrict__ x, const float* __restrict__ gamma,
        const float* __restrict__ beta, __hip_bfloat16* __restrict__ out) {
    const int row  = (blockIdx.x << 2) + (threadIdx.x >> 6);
    const int lane = threadIdx.x & 63;
    const float4* px = (const float4*)(x + (size_t)row * 1024);
    float4 v[4];
    float s = 0.f;
#pragma unroll
    for (int i = 0; i < 4; ++i) {
        v[i] = px[lane + (i << 6)];
        s += v[i].x + v[i].y + v[i].z + v[i].w;
    }
#pragma unroll
    for (int o = 32; o; o >>= 1) s += __shfl_xor(s, o, 64);
    const float mu = s * (1.0f / 1024.0f);
    float vs = 0.f;
#pragma unroll
    for (int i = 0; i < 4; ++i) {
        float a = v[i].x - mu, b = v[i].y - mu, c = v[i].z - mu, d = v[i].w - mu;
        vs += a * a + b * b + c * c + d * d;
    }
#pragma unroll
    for (int o = 32; o; o >>= 1) vs += __shfl_xor(vs, o, 64);
    const float rs = rsqrtf(vs * (1.0f / 1024.0f) + 1e-5f);
    const float4* pg = (const float4*)gamma;
    const float4* pb = (const float4*)beta;
    bh4* po = (bh4*)(out + (size_t)row * 1024);
#pragma unroll
    for (int i = 0; i < 4; ++i) {
        const int idx = lane + (i << 6);
        float4 g = pg[idx], bb = pb[idx];
        bh4 r;
        r.x = __float2bfloat16((v[i].x - mu) * rs * g.x + bb.x);
        r.y = __float2bfloat16((v[i].y - mu) * rs * g.y + bb.y);
        r.z = __float2bfloat16((v[i].z - mu) * rs * g.z + bb.z);
        r.w = __float2bfloat16((v[i].w - mu) * rs * g.w + bb.w);
        po[idx] = r;
    }
}

// ---------------- cast both weight matrices fp32 -> bf16 ----------------
__global__ __launch_bounds__(256) void cvt_kernel(
        const float* __restrict__ w1, const float* __restrict__ w2,
        __hip_bfloat16* __restrict__ o1, __hip_bfloat16* __restrict__ o2) {
    const int i = blockIdx.x * 256 + threadIdx.x;   // each handles 4 elems
    float4 a = ((const float4*)w1)[i];
    float4 b = ((const float4*)w2)[i];
    bh4 r1, r2;
    r1.x = __float2bfloat16(a.x); r1.y = __float2bfloat16(a.y);
    r1.z = __float2bfloat16(a.z); r1.w = __float2bfloat16(a.w);
    r2.x = __float2bfloat16(b.x); r2.y = __float2bfloat16(b.y);
    r2.z = __float2bfloat16(b.z); r2.w = __float2bfloat16(b.w);
    ((bh4*)o1)[i] = r1;
    ((bh4*)o2)[i] = r2;
}

// ---------------- GEMM (B^T weights), 128x128 tile, BK=32, MFMA 16x16x32 bf16 ----
// EPI==0: out_bf16 = gelu(A*B^T + bias)          (exact erf gelu)
// EPI==1: out_f32  = A*B^T + bias + resid
template <int EPI>
__global__ __launch_bounds__(256) void gemm_kernel(
        const __hip_bfloat16* __restrict__ A,    // M x K bf16, row-major
        const __hip_bfloat16* __restrict__ B,    // N x K bf16, row-major (torch [out,in])
        const float* __restrict__ bias,          // N
        const float* __restrict__ resid,         // M x N fp32 (EPI==1)
        __hip_bfloat16* __restrict__ outb,       // M x N bf16 (EPI==0)
        float* __restrict__ outf) {              // M x N fp32 (EPI==1)
    constexpr int K = 1024, N = 1024;
    __shared__ __align__(16) __hip_bfloat16 sA[128 * 32];
    __shared__ __align__(16) __hip_bfloat16 sB[128 * 32];

    const int tid  = threadIdx.x;
    const int lane = tid & 63;
    const int w    = tid >> 6;
    const int wm   = (w >> 1) * 64;   // wave's row base in tile
    const int wn   = (w & 1) * 64;    // wave's col base in tile
    const int bm   = blockIdx.y * 128;
    const int bn   = blockIdx.x * 128;

    // staging: thread t loads 16B; row = t>>2 (64 rows/inst), col8 = (t&3)*8
    const int lr = tid >> 2;
    const int lc = (tid & 3) * 8;
    const __hip_bfloat16* ga = A + (size_t)(bm + lr) * K + lc;
    const __hip_bfloat16* gb = B + (size_t)(bn + lr) * K + lc;
    char* la = (char*)sA + tid * 16;
    char* lb = (char*)sB + tid * 16;

    f32x4 acc[4][4] = {};

    const int fr = lane & 15;          // fragment row (A) / col (B)
    const int fk = (lane >> 4) * 8;    // fragment k offset

    for (int kt = 0; kt < K; kt += 32) {
        load16(ga + kt,                 la);
        load16(ga + kt + (size_t)64*K,  la + 4096);
        load16(gb + kt,                 lb);
        load16(gb + kt + (size_t)64*K,  lb + 4096);
        __syncthreads();   // drains vmcnt: staged tiles visible
        bf16x8 af[4], bfr[4];
#pragma unroll
        for (int i = 0; i < 4; ++i) {
            af[i]  = *(const bf16x8*)&sA[(wm + i * 16 + fr) * 32 + fk];
            bfr[i] = *(const bf16x8*)&sB[(wn + i * 16 + fr) * 32 + fk];
        }
#pragma unroll
        for (int i = 0; i < 4; ++i)
#pragma unroll
            for (int j = 0; j < 4; ++j)
                acc[i][j] = __builtin_amdgcn_mfma_f32_16x16x32_bf16(af[i], bfr[j], acc[i][j], 0, 0, 0);
        __syncthreads();   // all reads done before next stage overwrites
    }

    // epilogue: C/D layout col=lane&15, row=(lane>>4)*4+reg  [m89/m91 verified]
    const int cr = (lane >> 4) * 4;
    const int cc = lane & 15;
#pragma unroll
    for (int i = 0; i < 4; ++i) {
#pragma unroll
        for (int r = 0; r < 4; ++r) {
            const size_t grow = (size_t)(bm + wm + i * 16 + cr + r);
#pragma unroll
            for (int j = 0; j < 4; ++j) {
                const int gcol = bn + wn + j * 16 + cc;
                float v = acc[i][j][r] + bias[gcol];
                if (EPI == 0) {
                    float g = 0.5f * v * (1.0f + erff(v * 0.70710678118654752f));
                    outb[grow * N + gcol] = __float2bfloat16(g);
                } else {
                    outf[grow * N + gcol] = v + resid[grow * N + gcol];
                }
            }
        }
    }
}

extern "C" void kernel_launch(void* const* d_in, const int* in_sizes, int n_in,
                              void* d_out, int out_size, void* d_ws, size_t ws_size,
                              hipStream_t stream) {
    const float* x     = (const float*)d_in[0];
    const float* gamma = (const float*)d_in[1];
    const float* beta  = (const float*)d_in[2];
    const float* w1    = (const float*)d_in[3];
    const float* b1    = (const float*)d_in[4];
    const float* w2    = (const float*)d_in[5];
    const float* b2    = (const float*)d_in[6];
    float* out = (float*)d_out;

    const int M = in_sizes[0] / 1024;   // 16384

    // workspace layout
    char* ws = (char*)d_ws;
    __hip_bfloat16* hn  = (__hip_bfloat16*)ws;                          // M*1024*2 = 32 MiB
    __hip_bfloat16* h1  = (__hip_bfloat16*)(ws + (size_t)M * 2048);     // 32 MiB
    __hip_bfloat16* w1b = (__hip_bfloat16*)(ws + (size_t)M * 4096);     // 2 MiB
    __hip_bfloat16* w2b = (__hip_bfloat16*)(ws + (size_t)M * 4096 + 2097152);

    ln_kernel<<<M / 4, 256, 0, stream>>>(x, gamma, beta, hn);
    cvt_kernel<<<1024, 256, 0, stream>>>(w1, w2, w1b, w2b);
    gemm_kernel<0><<<dim3(8, M / 128), 256, 0, stream>>>(hn, w1b, b1, nullptr, h1, nullptr);
    gemm_kernel<1><<<dim3(8, M / 128), 256, 0, stream>>>(h1, w2b, b2, x, nullptr, out);
}